// Round 1
// baseline (2805.788 us; speedup 1.0000x reference)
//
#include <hip/hip_runtime.h>
#include <hip/hip_cooperative_groups.h>
#include <math.h>

namespace cg = cooperative_groups;

#define EMBED  1024
#define HIDDEN 1024
#define VOCAB  32000
#define TSTEPS 64
#define G4     4096   // 4*HIDDEN

// ---------------------------------------------------------------------------
// Kernel 1: build xs[t] = (t==0 ? features : embed_table[captions[t-1]])
// grid (64, 4) x 256 threads
// ---------------------------------------------------------------------------
__global__ void build_xs(const int* __restrict__ caps,
                         const float* __restrict__ feat,
                         const float* __restrict__ table,
                         float* __restrict__ xs) {
    int t = blockIdx.x;
    int e = threadIdx.x + blockIdx.y * 256;
    float v;
    if (t == 0) {
        v = feat[e];
    } else {
        size_t row = (size_t)caps[t - 1];
        v = table[row * EMBED + e];
    }
    xs[(size_t)t * EMBED + e] = v;
}

// ---------------------------------------------------------------------------
// Kernel 2: Xg[t][j] = dot(xs[t], W_ih[j]) + b_ih[j] + b_hh[j]
// grid 256 blocks (16 j-rows each) x 256 threads; each thread: 1 j x 4 t
// ---------------------------------------------------------------------------
__global__ __launch_bounds__(256) void xg_gemm(const float* __restrict__ xs,
                                               const float* __restrict__ Wih,
                                               const float* __restrict__ bih,
                                               const float* __restrict__ bhh,
                                               float* __restrict__ Xg) {
    __shared__ float xs_s[64][132];   // 128-wide e-chunk, +4 pad breaks bank aliasing
    int tid = threadIdx.x;
    int jl  = tid & 15;               // 0..15  local j
    int tg  = tid >> 4;               // 0..15  -> t_base = tg*4
    int j   = blockIdx.x * 16 + jl;
    const float* wrow = Wih + (size_t)j * EMBED;
    float acc[4] = {0.f, 0.f, 0.f, 0.f};

    for (int c = 0; c < 8; ++c) {     // 8 chunks of 128 e
        __syncthreads();
        for (int idx = tid; idx < 64 * 32; idx += 256) {
            int r = idx >> 5, f4 = idx & 31;
            float4 v = ((const float4*)(xs + (size_t)r * EMBED + c * 128))[f4];
            *((float4*)&xs_s[r][f4 * 4]) = v;
        }
        __syncthreads();
        for (int f4 = 0; f4 < 32; ++f4) {
            float4 w = ((const float4*)(wrow + c * 128))[f4];
#pragma unroll
            for (int k = 0; k < 4; ++k) {
                const float* xr = &xs_s[tg * 4 + k][f4 * 4];
                acc[k] += w.x * xr[0] + w.y * xr[1] + w.z * xr[2] + w.w * xr[3];
            }
        }
    }
    float bias = bih[j] + bhh[j];
#pragma unroll
    for (int k = 0; k < 4; ++k) {
        Xg[(size_t)(tg * 4 + k) * G4 + j] = acc[k] + bias;
    }
}

// ---------------------------------------------------------------------------
// Kernel 3: sequential LSTM. Cooperative launch, 256 blocks x 256 threads.
// Block b owns h-indices [4b, 4b+4): 16 gate rows of W_hh (64 KB -> 2 MB/XCD L2).
// wave wv (0..3) = gate; within wave: q = lane>>4 (h sub-index), c16 = lane&15
// each lane dots 64 elems (16 float4), 4-step shuffle reduce over 16 lanes.
// h exchanged via agent-scope atomics (per-XCD L2s non-coherent).
// ---------------------------------------------------------------------------
__global__ __launch_bounds__(256, 1) void lstm_seq(const float* __restrict__ Xg,
                                                   const float* __restrict__ Whh,
                                                   float* hbuf,   // 2*1024, zeroed
                                                   float* __restrict__ hs) {
    cg::grid_group grid = cg::this_grid();
    __shared__ float h_s[HIDDEN];
    __shared__ float gate_s[4][4];

    int tid  = threadIdx.x;
    int lane = tid & 63;
    int wv   = tid >> 6;          // gate index 0..3 (i,f,g,o)
    int q    = lane >> 4;         // 0..3
    int c16  = lane & 15;
    int q0   = blockIdx.x * 4;
    int row  = wv * HIDDEN + q0 + q;
    const float4* wrow = (const float4*)(Whh + (size_t)row * HIDDEN);

    float cstate = 0.0f;          // live in tid<4 only
    float* hprev = hbuf;          // zero-initialized by memset
    float* hnext = hbuf + HIDDEN;

    for (int t = 0; t < TSTEPS; ++t) {
        // stage h (agent-scope: bypass non-coherent L1/L2, read LLC)
        for (int i = tid; i < HIDDEN; i += 256) {
            h_s[i] = __hip_atomic_load(hprev + i, __ATOMIC_RELAXED,
                                       __HIP_MEMORY_SCOPE_AGENT);
        }
        __syncthreads();

        float sum = 0.f;
#pragma unroll
        for (int k = 0; k < 16; ++k) {
            float4 w = wrow[c16 + 16 * k];
            const float* hv = &h_s[(c16 + 16 * k) * 4];
            sum += w.x * hv[0] + w.y * hv[1] + w.z * hv[2] + w.w * hv[3];
        }
        sum += __shfl_xor(sum, 1);
        sum += __shfl_xor(sum, 2);
        sum += __shfl_xor(sum, 4);
        sum += __shfl_xor(sum, 8);
        if (c16 == 0) gate_s[wv][q] = sum;
        __syncthreads();

        if (tid < 4) {
            int hj = q0 + tid;
            const float* xg = Xg + (size_t)t * G4;
            float gi = gate_s[0][tid] + xg[hj];
            float gf = gate_s[1][tid] + xg[HIDDEN + hj];
            float gg = gate_s[2][tid] + xg[2 * HIDDEN + hj];
            float go = gate_s[3][tid] + xg[3 * HIDDEN + hj];
            float i_ = 1.f / (1.f + expf(-gi));
            float f_ = 1.f / (1.f + expf(-gf));
            float g_ = tanhf(gg);
            float o_ = 1.f / (1.f + expf(-go));
            cstate = f_ * cstate + i_ * g_;
            float hv = o_ * tanhf(cstate);
            __hip_atomic_store(hnext + hj, hv, __ATOMIC_RELAXED,
                               __HIP_MEMORY_SCOPE_AGENT);
            hs[(size_t)t * HIDDEN + hj] = hv;
            __threadfence();
        }
        float* tmp = hprev; hprev = hnext; hnext = tmp;
        grid.sync();
    }
}

// ---------------------------------------------------------------------------
// Kernel 4: logits = hs @ fc_W.T + fc_b   [64,1024] x [1024,32000]
// grid 1000 blocks (32 v-rows each) x 256 threads; thread: 1 v x 8 t
// ---------------------------------------------------------------------------
__global__ __launch_bounds__(256) void logits_gemm(const float* __restrict__ hs,
                                                   const float* __restrict__ fcW,
                                                   const float* __restrict__ fcb,
                                                   float* __restrict__ out) {
    __shared__ float hs_s[64][132];
    int tid = threadIdx.x;
    int vl  = tid & 31;           // 0..31 local v
    int tg  = tid >> 5;           // 0..7 -> t_base = tg*8
    int v   = blockIdx.x * 32 + vl;
    const float* wrow = fcW + (size_t)v * HIDDEN;
    float acc[8] = {0.f, 0.f, 0.f, 0.f, 0.f, 0.f, 0.f, 0.f};

    for (int c = 0; c < 8; ++c) {
        __syncthreads();
        for (int idx = tid; idx < 64 * 32; idx += 256) {
            int r = idx >> 5, f4 = idx & 31;
            float4 h4 = ((const float4*)(hs + (size_t)r * HIDDEN + c * 128))[f4];
            *((float4*)&hs_s[r][f4 * 4]) = h4;
        }
        __syncthreads();
        for (int f4 = 0; f4 < 32; ++f4) {
            float4 w = ((const float4*)(wrow + c * 128))[f4];
#pragma unroll
            for (int k = 0; k < 8; ++k) {
                const float* hv = &hs_s[tg * 8 + k][f4 * 4];
                acc[k] += w.x * hv[0] + w.y * hv[1] + w.z * hv[2] + w.w * hv[3];
            }
        }
    }
    float b = fcb[v];
#pragma unroll
    for (int k = 0; k < 8; ++k) {
        out[(size_t)(tg * 8 + k) * VOCAB + v] = acc[k] + b;
    }
}

// ---------------------------------------------------------------------------
extern "C" void kernel_launch(void* const* d_in, const int* in_sizes, int n_in,
                              void* d_out, int out_size, void* d_ws, size_t ws_size,
                              hipStream_t stream) {
    const int*   caps  = (const int*)  d_in[0];
    const float* feat  = (const float*)d_in[1];
    const float* table = (const float*)d_in[2];
    const float* Wih   = (const float*)d_in[3];
    const float* Whh   = (const float*)d_in[4];
    const float* bih   = (const float*)d_in[5];
    const float* bhh   = (const float*)d_in[6];
    const float* fcW   = (const float*)d_in[7];
    const float* fcb   = (const float*)d_in[8];
    float* out = (float*)d_out;

    char* ws = (char*)d_ws;
    float* xs   = (float*)(ws);                                  // 256 KB
    float* Xg   = (float*)(ws + 262144);                         // 1 MB
    float* hs   = (float*)(ws + 262144 + 1048576);               // 256 KB
    float* hbuf = (float*)(ws + 262144 + 1048576 + 262144);      // 8 KB

    // ws is poisoned 0xAA before every timed call: zero the h double-buffer.
    hipMemsetAsync(hbuf, 0, 2 * HIDDEN * sizeof(float), stream);

    build_xs<<<dim3(TSTEPS, 4), 256, 0, stream>>>(caps, feat, table, xs);
    xg_gemm <<<256, 256, 0, stream>>>(xs, Wih, bih, bhh, Xg);

    void* args[] = {(void*)&Xg, (void*)&Whh, (void*)&hbuf, (void*)&hs};
    hipLaunchCooperativeKernel(lstm_seq, dim3(256), dim3(256), args, 0u, stream);

    logits_gemm<<<VOCAB / 32, 256, 0, stream>>>(hs, fcW, fcb, out);
}

// Round 2
// 1074.004 us; speedup vs baseline: 2.6125x; 2.6125x over previous
//
#include <hip/hip_runtime.h>
#include <hip/hip_cooperative_groups.h>
#include <math.h>

namespace cg = cooperative_groups;

#define EMBED  1024
#define HIDDEN 1024
#define VOCAB  32000
#define TSTEPS 64
#define G4     4096   // 4*HIDDEN
#define NBLK   256    // lstm blocks (1 per CU, cooperative-resident)

// ---------------------------------------------------------------------------
// Kernel 1: build xs[t] = (t==0 ? features : embed_table[captions[t-1]])
// ---------------------------------------------------------------------------
__global__ void build_xs(const int* __restrict__ caps,
                         const float* __restrict__ feat,
                         const float* __restrict__ table,
                         float* __restrict__ xs) {
    int t = blockIdx.x;
    int e = threadIdx.x + blockIdx.y * 256;
    float v;
    if (t == 0) {
        v = feat[e];
    } else {
        size_t row = (size_t)caps[t - 1];
        v = table[row * EMBED + e];
    }
    xs[(size_t)t * EMBED + e] = v;
}

// ---------------------------------------------------------------------------
// Kernel 2: Xg[t][j] = dot(xs[t], W_ih[j]) + b_ih[j] + b_hh[j]
// ---------------------------------------------------------------------------
__global__ __launch_bounds__(256) void xg_gemm(const float* __restrict__ xs,
                                               const float* __restrict__ Wih,
                                               const float* __restrict__ bih,
                                               const float* __restrict__ bhh,
                                               float* __restrict__ Xg) {
    __shared__ float xs_s[64][132];
    int tid = threadIdx.x;
    int jl  = tid & 15;
    int tg  = tid >> 4;
    int j   = blockIdx.x * 16 + jl;
    const float* wrow = Wih + (size_t)j * EMBED;
    float acc[4] = {0.f, 0.f, 0.f, 0.f};

    for (int c = 0; c < 8; ++c) {
        __syncthreads();
        for (int idx = tid; idx < 64 * 32; idx += 256) {
            int r = idx >> 5, f4 = idx & 31;
            float4 v = ((const float4*)(xs + (size_t)r * EMBED + c * 128))[f4];
            *((float4*)&xs_s[r][f4 * 4]) = v;
        }
        __syncthreads();
        for (int f4 = 0; f4 < 32; ++f4) {
            float4 w = ((const float4*)(wrow + c * 128))[f4];
#pragma unroll
            for (int k = 0; k < 4; ++k) {
                const float* xr = &xs_s[tg * 4 + k][f4 * 4];
                acc[k] += w.x * xr[0] + w.y * xr[1] + w.z * xr[2] + w.w * xr[3];
            }
        }
    }
    float bias = bih[j] + bhh[j];
#pragma unroll
    for (int k = 0; k < 4; ++k) {
        Xg[(size_t)(tg * 4 + k) * G4 + j] = acc[k] + bias;
    }
}

// ---------------------------------------------------------------------------
// Kernel 3: sequential LSTM, 256 blocks x 256 threads (cooperative launch for
// the co-residency guarantee only — grid.sync() replaced by a hand-rolled
// monotonic counter barrier: ~1 LLC round trip instead of ~38 us).
// W_hh slice (64 floats/thread = 16 float4 VGPRs) register-resident across t.
// h exchanged via agent-scope atomics (per-XCD L2s non-coherent).
// ---------------------------------------------------------------------------
__global__ __launch_bounds__(256, 1) void lstm_seq(const float* __restrict__ Xg,
                                                   const float* __restrict__ Whh,
                                                   float* hbuf,       // 2*1024 f
                                                   float* __restrict__ hs,
                                                   unsigned* barrier_cnt) {
    __shared__ float h_s[HIDDEN];
    __shared__ float gate_s[4][4];

    int tid  = threadIdx.x;
    int lane = tid & 63;
    int wv   = tid >> 6;          // gate index 0..3 (i,f,g,o)
    int q    = lane >> 4;         // 0..3
    int c16  = lane & 15;
    int q0   = blockIdx.x * 4;
    int row  = wv * HIDDEN + q0 + q;
    const float4* wrow = (const float4*)(Whh + (size_t)row * HIDDEN);

    // Cache this lane's 64-float W_hh slice in registers (read once from HBM).
    float4 wreg[16];
#pragma unroll
    for (int k = 0; k < 16; ++k) wreg[k] = wrow[c16 + 16 * k];

    float cstate = 0.0f;          // live in tid<4 only
    float* hprev = hbuf;          // zero-initialized by memset
    float* hnext = hbuf + HIDDEN;

    for (int t = 0; t < TSTEPS; ++t) {
        // stage h (agent-scope: bypass non-coherent L1/L2, read LLC)
        for (int i = tid; i < HIDDEN; i += 256) {
            h_s[i] = __hip_atomic_load(hprev + i, __ATOMIC_RELAXED,
                                       __HIP_MEMORY_SCOPE_AGENT);
        }
        __syncthreads();

        float sum = 0.f;
#pragma unroll
        for (int k = 0; k < 16; ++k) {
            float4 w = wreg[k];
            const float* hv = &h_s[(c16 + 16 * k) * 4];
            sum += w.x * hv[0] + w.y * hv[1] + w.z * hv[2] + w.w * hv[3];
        }
        sum += __shfl_xor(sum, 1);
        sum += __shfl_xor(sum, 2);
        sum += __shfl_xor(sum, 4);
        sum += __shfl_xor(sum, 8);
        if (c16 == 0) gate_s[wv][q] = sum;
        __syncthreads();

        if (tid < 4) {
            int hj = q0 + tid;
            const float* xg = Xg + (size_t)t * G4;
            float gi = gate_s[0][tid] + xg[hj];
            float gf = gate_s[1][tid] + xg[HIDDEN + hj];
            float gg = gate_s[2][tid] + xg[2 * HIDDEN + hj];
            float go = gate_s[3][tid] + xg[3 * HIDDEN + hj];
            float i_ = 1.f / (1.f + expf(-gi));
            float f_ = 1.f / (1.f + expf(-gf));
            float g_ = tanhf(gg);
            float o_ = 1.f / (1.f + expf(-go));
            cstate = f_ * cstate + i_ * g_;
            float hv = o_ * tanhf(cstate);
            __hip_atomic_store(hnext + hj, hv, __ATOMIC_RELAXED,
                               __HIP_MEMORY_SCOPE_AGENT);
            hs[(size_t)t * HIDDEN + hj] = hv;
        }
        __syncthreads();   // all stores issued (s_barrier drains vmcnt)

        // ---- hand-rolled grid barrier: monotonic counter, no sense reversal
        if (tid == 0) {
            __hip_atomic_fetch_add(barrier_cnt, 1u, __ATOMIC_RELEASE,
                                   __HIP_MEMORY_SCOPE_AGENT);
            unsigned target = (unsigned)NBLK * (unsigned)(t + 1);
            while (__hip_atomic_load(barrier_cnt, __ATOMIC_ACQUIRE,
                                     __HIP_MEMORY_SCOPE_AGENT) < target) {
                __builtin_amdgcn_s_sleep(1);
            }
        }
        __syncthreads();

        float* tmp = hprev; hprev = hnext; hnext = tmp;
    }
}

// ---------------------------------------------------------------------------
// Kernel 4: logits = hs @ fc_W.T + fc_b   [64,1024] x [1024,32000]
// ---------------------------------------------------------------------------
__global__ __launch_bounds__(256) void logits_gemm(const float* __restrict__ hs,
                                                   const float* __restrict__ fcW,
                                                   const float* __restrict__ fcb,
                                                   float* __restrict__ out) {
    __shared__ float hs_s[64][132];
    int tid = threadIdx.x;
    int vl  = tid & 31;
    int tg  = tid >> 5;
    int v   = blockIdx.x * 32 + vl;
    const float* wrow = fcW + (size_t)v * HIDDEN;
    float acc[8] = {0.f, 0.f, 0.f, 0.f, 0.f, 0.f, 0.f, 0.f};

    for (int c = 0; c < 8; ++c) {
        __syncthreads();
        for (int idx = tid; idx < 64 * 32; idx += 256) {
            int r = idx >> 5, f4 = idx & 31;
            float4 h4 = ((const float4*)(hs + (size_t)r * HIDDEN + c * 128))[f4];
            *((float4*)&hs_s[r][f4 * 4]) = h4;
        }
        __syncthreads();
        for (int f4 = 0; f4 < 32; ++f4) {
            float4 w = ((const float4*)(wrow + c * 128))[f4];
#pragma unroll
            for (int k = 0; k < 8; ++k) {
                const float* hv = &hs_s[tg * 8 + k][f4 * 4];
                acc[k] += w.x * hv[0] + w.y * hv[1] + w.z * hv[2] + w.w * hv[3];
            }
        }
    }
    float b = fcb[v];
#pragma unroll
    for (int k = 0; k < 8; ++k) {
        out[(size_t)(tg * 8 + k) * VOCAB + v] = acc[k] + b;
    }
}

// ---------------------------------------------------------------------------
extern "C" void kernel_launch(void* const* d_in, const int* in_sizes, int n_in,
                              void* d_out, int out_size, void* d_ws, size_t ws_size,
                              hipStream_t stream) {
    const int*   caps  = (const int*)  d_in[0];
    const float* feat  = (const float*)d_in[1];
    const float* table = (const float*)d_in[2];
    const float* Wih   = (const float*)d_in[3];
    const float* Whh   = (const float*)d_in[4];
    const float* bih   = (const float*)d_in[5];
    const float* bhh   = (const float*)d_in[6];
    const float* fcW   = (const float*)d_in[7];
    const float* fcb   = (const float*)d_in[8];
    float* out = (float*)d_out;

    char* ws = (char*)d_ws;
    float*    xs   = (float*)(ws);                                  // 256 KB
    float*    Xg   = (float*)(ws + 262144);                         // 1 MB
    float*    hs   = (float*)(ws + 262144 + 1048576);               // 256 KB
    float*    hbuf = (float*)(ws + 262144 + 1048576 + 262144);      // 8 KB
    unsigned* cnt  = (unsigned*)(ws + 262144 + 1048576 + 262144 + 8192);

    // ws is poisoned 0xAA before every timed call: zero h double-buffer + cnt.
    hipMemsetAsync(hbuf, 0, 2 * HIDDEN * sizeof(float) + 64, stream);

    build_xs<<<dim3(TSTEPS, 4), 256, 0, stream>>>(caps, feat, table, xs);
    xg_gemm <<<256, 256, 0, stream>>>(xs, Wih, bih, bhh, Xg);

    void* args[] = {(void*)&Xg, (void*)&Whh, (void*)&hbuf, (void*)&hs, (void*)&cnt};
    hipLaunchCooperativeKernel(lstm_seq, dim3(NBLK), dim3(256), args, 0u, stream);

    logits_gemm<<<VOCAB / 32, 256, 0, stream>>>(hs, fcW, fcb, out);
}